// Round 10
// baseline (67.316 us; speedup 1.0000x reference)
//
#include <hip/hip_runtime.h>
#include <math.h>

typedef _Float16 half8 __attribute__((ext_vector_type(8)));
typedef _Float16 half4 __attribute__((ext_vector_type(4)));
typedef float    f32x4 __attribute__((ext_vector_type(4)));

#define TOKENS  32768
#define HIDDEN  2048
#define EXPERTS 64
#define TOPK    8
#define BKW     64               // k per staged window
#define NWIN    (HIDDEN / BKW)   // 32
#define LDH     72               // LDS row stride in halves (144 B: 16B-aligned)

// ---------------------------------------------------------------------------
// Kernel 1: split W fp32 -> (Whi, Wlo) fp16, row-major [64][2048] in d_ws.
// ---------------------------------------------------------------------------
__global__ void wsplit(const float* __restrict__ W,
                       _Float16* __restrict__ whi, _Float16* __restrict__ wlo) {
    int i = blockIdx.x * 256 + threadIdx.x;     // 0..131071
    float w = W[i];
    _Float16 h = (_Float16)w;
    whi[i] = h;
    wlo[i] = (_Float16)(w - (float)h);
}

// ---------------------------------------------------------------------------
// Kernel 2: MFMA router via fp16x3 split (hi*hi + hi*lo + lo*hi, fp32 acc).
// r9 change vs r8: 512-thr blocks (8 waves). Wave (ts,eh) = 16-token slab x
// 32-expert half; acc = 2 x f32x4 (8 VGPR). Per-thread staging halves to
// 2 x float4 (A) + 2 x half8 (W) -> live set ~60 regs -> 2-4 blocks/CU
// resident; barrier/HBM-latency stalls hidden by cross-block TLP.
// Same single-buffered LDS (36.9 KB), 2 barriers/window, 1-window prefetch.
// ---------------------------------------------------------------------------
__global__ __launch_bounds__(512, 1)
void router_mfma8(const float* __restrict__ A,
                  const _Float16* __restrict__ Wh,
                  const _Float16* __restrict__ Wl,
                  const float* __restrict__ bias,
                  float* __restrict__ out) {
    __shared__ __align__(16) _Float16 hsm[4 * 64 * LDH];   // Ahi|Alo|Whi|Wlo
    _Float16* Ahs = hsm;
    _Float16* Als = hsm + 64 * LDH;
    _Float16* Whs = hsm + 2 * 64 * LDH;
    _Float16* Wls = hsm + 3 * 64 * LDH;

    const int tid = threadIdx.x;
    const int wv  = tid >> 6;
    const int l   = tid & 63;
    const int g   = blockIdx.x;
    const int ts  = wv & 3;            // token slab: rows ts*16..ts*16+15
    const int eh  = wv >> 2;           // expert half: experts eh*32..eh*32+31

    // staging maps (512 threads)
    const int ar = tid >> 3;           // 0..63 token row; chunks ac, ac+8
    const int ac = tid & 7;
    const int wr = tid >> 3;           // 0..63 expert row; half8 chunk wc
    const int wc = tid & 7;

    const float*    Abase  = A  + ((size_t)g * 64 + ar) * HIDDEN;
    const _Float16* WhBase = Wh + (size_t)wr * HIDDEN;
    const _Float16* WlBase = Wl + (size_t)wr * HIDDEN;

    f32x4 acc[2];
    acc[0] = (f32x4){0.f, 0.f, 0.f, 0.f};
    acc[1] = (f32x4){0.f, 0.f, 0.f, 0.f};

    float4 a0r, a1r;                   // A staging regs (2 chunks of own row)
    half8 whr, wlr;                    // W staging regs

    #define LOADA(win) do {                                                  \
        a0r = *(const float4*)(Abase + (win) * BKW + ac * 4);                \
        a1r = *(const float4*)(Abase + (win) * BKW + (ac + 8) * 4);          \
    } while (0)
    #define LOADW(win) do {                                                  \
        whr = *(const half8*)(WhBase + (win) * BKW + wc * 8);                \
        wlr = *(const half8*)(WlBase + (win) * BKW + wc * 8);                \
    } while (0)
    #define CVT1(v, col) do {                                                \
        _Float16 h0_ = (_Float16)(v).x, h1_ = (_Float16)(v).y;               \
        _Float16 h2_ = (_Float16)(v).z, h3_ = (_Float16)(v).w;               \
        half4 hh_ = {h0_, h1_, h2_, h3_};                                    \
        half4 ll_ = {(_Float16)((v).x - (float)h0_),                         \
                     (_Float16)((v).y - (float)h1_),                         \
                     (_Float16)((v).z - (float)h2_),                         \
                     (_Float16)((v).w - (float)h3_)};                        \
        *(half4*)(&Ahs[ar * LDH + (col) * 4]) = hh_;                         \
        *(half4*)(&Als[ar * LDH + (col) * 4]) = ll_;                         \
    } while (0)

    LOADA(0);
    LOADW(0);

    #pragma unroll 1
    for (int win = 0; win < NWIN; ++win) {
        __syncthreads();                       // previous window fully consumed
        CVT1(a0r, ac);
        CVT1(a1r, ac + 8);
        *(half8*)(&Whs[wr * LDH + wc * 8]) = whr;
        *(half8*)(&Wls[wr * LDH + wc * 8]) = wlr;
        __syncthreads();                       // window published

        if (win + 1 < NWIN) {                  // next-window loads fly during MFMA
            LOADA(win + 1);
            LOADW(win + 1);
        }

        #pragma unroll
        for (int ks = 0; ks < 2; ++ks) {
            const int ko = ks * 32 + (l >> 4) * 8;
            half8 ahi = *(const half8*)(&Ahs[(ts * 16 + (l & 15)) * LDH + ko]);
            half8 alo = *(const half8*)(&Als[(ts * 16 + (l & 15)) * LDH + ko]);
            #pragma unroll
            for (int n = 0; n < 2; ++n) {
                const int brow = eh * 32 + n * 16 + (l & 15);
                half8 bh = *(const half8*)(&Whs[brow * LDH + ko]);
                half8 bl = *(const half8*)(&Wls[brow * LDH + ko]);
                acc[n] = __builtin_amdgcn_mfma_f32_16x16x32_f16(ahi, bh, acc[n], 0, 0, 0);
                acc[n] = __builtin_amdgcn_mfma_f32_16x16x32_f16(ahi, bl, acc[n], 0, 0, 0);
                acc[n] = __builtin_amdgcn_mfma_f32_16x16x32_f16(alo, bh, acc[n], 0, 0, 0);
            }
        }
    }
    #undef LOADA
    #undef LOADW
    #undef CVT1

    // ---- epilogue: logits (+bias) to LDS, top-8 + softmax + scatter ----
    __syncthreads();                           // staging LDS dead; alias as float
    float* lg = (float*)hsm;                   // [64 tok][68]
    float* sc = (float*)hsm + 64 * 68;         // [64 tok][65]

    // D layout (m89): col = lane&15, row = (lane>>4)*4 + q
    #pragma unroll
    for (int n = 0; n < 2; ++n) {
        const int ecol = eh * 32 + n * 16 + (l & 15);
        float b = bias[ecol];
        #pragma unroll
        for (int q = 0; q < 4; ++q) {
            int trow = ts * 16 + (l >> 4) * 4 + q;
            lg[trow * 68 + ecol] = acc[n][q] + b;
        }
    }
    for (int i = tid; i < 64 * 65; i += 512) sc[i] = 0.f;
    __syncthreads();

    if (tid < 64) {
        const int t = tid;
        float v[64];
        #pragma unroll
        for (int e = 0; e < 64; ++e) v[e] = lg[t * 68 + e];

        float tvals[TOPK]; int tix[TOPK]; float probs[TOPK];
        unsigned long long chosen = 0ull;
        #pragma unroll
        for (int j = 0; j < TOPK; ++j) {
            float best = -INFINITY; int bi = 0;
            #pragma unroll
            for (int e = 0; e < 64; ++e) {
                bool ok = ((chosen >> e) & 1ull) == 0ull;
                if (ok && v[e] > best) { best = v[e]; bi = e; }  // strict >: lowest idx on tie
            }
            chosen |= (1ull << bi);
            tvals[j] = best; tix[j] = bi;
        }
        float m = tvals[0];
        float ssum = 0.f;
        #pragma unroll
        for (int j = 0; j < TOPK; ++j) { probs[j] = __expf(tvals[j] - m); ssum += probs[j]; }
        float inv = 1.f / ssum;
        #pragma unroll
        for (int j = 0; j < TOPK; ++j) probs[j] *= inv;

        #pragma unroll
        for (int j = 0; j < TOPK; ++j) sc[t * 65 + tix[j]] = probs[j];

        float* oidx = out + (size_t)TOKENS * EXPERTS;
        const int token = g * 64 + t;
        #pragma unroll
        for (int j = 0; j < TOPK; ++j) oidx[(size_t)token * TOPK + j] = (float)tix[j];
    }
    __syncthreads();

    // ---- coalesced score write: 64 tokens x 64 experts = 1024 float4 ----
    float* oscore = out + (size_t)g * 4096;
    #pragma unroll
    for (int p = 0; p < 2; ++p) {
        int fi  = tid + 512 * p;               // float4 index 0..1023
        int tok = fi >> 4;
        int es  = (fi & 15) * 4;
        float4 vv;
        vv.x = sc[tok * 65 + es + 0];
        vv.y = sc[tok * 65 + es + 1];
        vv.z = sc[tok * 65 + es + 2];
        vv.w = sc[tok * 65 + es + 3];
        *(float4*)(oscore + (size_t)fi * 4) = vv;
    }
}

extern "C" void kernel_launch(void* const* d_in, const int* in_sizes, int n_in,
                              void* d_out, int out_size, void* d_ws, size_t ws_size,
                              hipStream_t stream) {
    const float* A    = (const float*)d_in[0];   // [32768, 2048] fp32
    const float* W    = (const float*)d_in[1];   // [64, 2048] fp32
    const float* bias = (const float*)d_in[2];   // [64] fp32
    float* out = (float*)d_out;                  // scores (32768*64) ++ idx (32768*8)

    _Float16* whi = (_Float16*)d_ws;             // 256 KB
    _Float16* wlo = whi + EXPERTS * HIDDEN;      // 256 KB

    wsplit<<<512, 256, 0, stream>>>(W, whi, wlo);
    router_mfma8<<<TOKENS / 64, 512, 0, stream>>>(A, whi, wlo, bias, out);
}